// Round 4
// baseline (538.358 us; speedup 1.0000x reference)
//
#include <hip/hip_runtime.h>

#define E_NUM 8
#define FFN_DIM 8192
#define D_DIM 2048
#define T_DIM 4096

using bf16x8 = __attribute__((ext_vector_type(8))) short;
using f32x4  = __attribute__((ext_vector_type(4))) float;
using u16x8  = __attribute__((ext_vector_type(8))) unsigned short;

__device__ __forceinline__ unsigned short f2bf(float f) {
  union { float f; unsigned int u; } v; v.f = f;
  unsigned int u = v.u;
  unsigned int r = (u + 0x7FFFu + ((u >> 16) & 1u)) >> 16;
  return (unsigned short)r;
}

__device__ __forceinline__ void gload16(const unsigned short* g, const unsigned short* l) {
  __builtin_amdgcn_global_load_lds(
      (const __attribute__((address_space(1))) void*)g,
      (__attribute__((address_space(3))) void*)l, 16, 0, 0);
}

// ---------- prep: fp32 -> bf16 convert (optionally slab-offset by *eidx) ----------
__global__ void convert_kernel(const float* __restrict__ src_base,
                               const int* __restrict__ eidx, long slab,
                               unsigned short* __restrict__ dst, long n) {
  const float* src = src_base + (long)(*eidx) * slab;
  long stride = (long)gridDim.x * blockDim.x;
  for (long i = (long)blockIdx.x * blockDim.x + threadIdx.x; i * 8 < n; i += stride) {
    long e = i * 8;
    const float4* p = (const float4*)(src + e);
    float4 f0 = p[0], f1 = p[1];
    u16x8 o;
    o[0] = f2bf(f0.x); o[1] = f2bf(f0.y); o[2] = f2bf(f0.z); o[3] = f2bf(f0.w);
    o[4] = f2bf(f1.x); o[5] = f2bf(f1.y); o[6] = f2bf(f1.z); o[7] = f2bf(f1.w);
    *(u16x8*)(dst + e) = o;
  }
}

// ---------- prep: transpose w2 slab (FFN,D) fp32 -> (D,FFN) bf16 ----------
__global__ void transpose_kernel(const float* __restrict__ w2,
                                 const int* __restrict__ eidx,
                                 unsigned short* __restrict__ dst) {
  __shared__ unsigned short tile[32][33];
  const float* src = w2 + (long)(*eidx) * (long)FFN_DIM * D_DIM;
  int d0 = blockIdx.x << 5;
  int f0 = blockIdx.y << 5;
  int tx = threadIdx.x & 31, ty = threadIdx.x >> 5;
#pragma unroll
  for (int i = 0; i < 4; ++i) {
    int f = ty + i * 8;
    tile[f][tx] = f2bf(src[(long)(f0 + f) * D_DIM + d0 + tx]);
  }
  __syncthreads();
#pragma unroll
  for (int i = 0; i < 4; ++i) {
    int d = ty + i * 8;
    dst[(long)(d0 + d) * FFN_DIM + f0 + tx] = tile[tx][d];
  }
}

#define VMCNT8 asm volatile("s_waitcnt vmcnt(8)" ::: "memory")
#define VMCNT6 asm volatile("s_waitcnt vmcnt(6)" ::: "memory")
#define VMCNT2 asm volatile("s_waitcnt vmcnt(2)" ::: "memory")
#define VMCNT0 asm volatile("s_waitcnt vmcnt(0)" ::: "memory")
#define BAR __builtin_amdgcn_s_barrier()

// ---------- GEMM1 fused, 4-phase, deep-issue (all 8 rounds at P0) ----------
// tile 256(m) x 128(n), BK=64, 8 waves (4M x 2N), per-wave dual 64x64 output.
// LDS: A 2x(256x64), B1 2x(128x64), B2 2x(128x64) bf16 = 128 KiB.
// Waits: end-P0 vmcnt(8) [B2-of-t, ~4.5 phases cover], end-P3 vmcnt(2)
// [rounds 0-5 of t+1, ~3.5 phases cover]. Never drains mid-loop.
__global__ __launch_bounds__(512, 2) void gemm1_silu(
    const unsigned short* __restrict__ Xb,    // (4096,2048)
    const unsigned short* __restrict__ W1b,   // (8192,2048)
    const unsigned short* __restrict__ V1b,   // (8192,2048)
    unsigned short* __restrict__ Hb) {        // (4096,8192)
  __shared__ __align__(16) unsigned short sA[2 * 256 * 64];
  __shared__ __align__(16) unsigned short sB1[2 * 128 * 64];
  __shared__ __align__(16) unsigned short sB2[2 * 128 * 64];

  const int tid = threadIdx.x;
  const int wv = tid >> 6, l = tid & 63;
  const int wm = wv >> 1, wn = wv & 1;
  const int kq = l >> 4, lr = l & 15;
  const int m0 = blockIdx.y << 8;
  const int n0 = blockIdx.x << 7;

  const int rsub = tid >> 3;
  const int sslot8 = ((tid & 7) ^ ((tid >> 3) & 7)) << 3;
  const unsigned short* gA0  = Xb  + (long)(m0 + rsub) * D_DIM + sslot8;
  const unsigned short* gB1r = W1b + (long)(n0 + rsub) * D_DIM + sslot8;
  const unsigned short* gB2r = V1b + (long)(n0 + rsub) * D_DIM + sslot8;

#define ST_A(r_)  gload16(gA0  + (long)((r_) * 64) * D_DIM + tc, sA  + sb * 16384 + (r_) * 4096 + wv * 512)
#define ST_B1(r_) gload16(gB1r + (long)((r_) * 64) * D_DIM + tc, sB1 + sb * 8192  + (r_) * 4096 + wv * 512)
#define ST_B2(r_) gload16(gB2r + (long)((r_) * 64) * D_DIM + tc, sB2 + sb * 8192  + (r_) * 4096 + wv * 512)

  int raoff[4], rboff[4];
#pragma unroll
  for (int m = 0; m < 4; ++m) {
    int row = wm * 64 + m * 16 + lr;
    raoff[m] = row * 64 + ((kq ^ (row & 7)) << 3);
  }
#pragma unroll
  for (int n = 0; n < 4; ++n) {
    int row = wn * 64 + n * 16 + lr;
    rboff[n] = row * 64 + ((kq ^ (row & 7)) << 3);
  }

  f32x4 acc1[4][4], acc2[4][4];
  f32x4 z = {0.f, 0.f, 0.f, 0.f};
#pragma unroll
  for (int m = 0; m < 4; ++m)
#pragma unroll
    for (int n = 0; n < 4; ++n) { acc1[m][n] = z; acc2[m][n] = z; }

  // prologue: stage tile 0 fully; wait rounds 0-5 (B2 stays outstanding)
  {
    int tc = 0, sb = 0;
    ST_A(0); ST_A(1); ST_A(2); ST_A(3);
    ST_B1(0); ST_B1(1); ST_B2(0); ST_B2(1);
    VMCNT2;
    BAR;
  }

  const int NT = D_DIM / 64;  // 32
  for (int t = 0; t < NT; ++t) {
    const int db = t & 1;
    const unsigned short* Ab  = sA  + db * 16384;
    const unsigned short* B1b = sB1 + db * 8192;
    const unsigned short* B2b = sB2 + db * 8192;
    const int pf = (t < NT - 1);
    const int tc = (t + 1) << 6;
    const int sb = db ^ 1;
    bf16x8 af[4], bf_[4];

    // ---- P0: frags A k0 + B1 k0; issue ALL 8 rounds for t+1; MFMA acc1 k0 ----
#pragma unroll
    for (int m = 0; m < 4; ++m) af[m] = *(const bf16x8*)(Ab + raoff[m]);
#pragma unroll
    for (int n = 0; n < 4; ++n) bf_[n] = *(const bf16x8*)(B1b + rboff[n]);
    if (pf) {
      ST_A(0); ST_A(1); ST_A(2); ST_A(3);
      ST_B1(0); ST_B1(1); ST_B2(0); ST_B2(1);
    }
    BAR;
    __builtin_amdgcn_s_setprio(1);
#pragma unroll
    for (int m = 0; m < 4; ++m)
#pragma unroll
      for (int n = 0; n < 4; ++n)
        acc1[m][n] = __builtin_amdgcn_mfma_f32_16x16x32_bf16(af[m], bf_[n], acc1[m][n], 0, 0, 0);
    __builtin_amdgcn_s_setprio(0);
    if (pf) { VMCNT8; } else { VMCNT0; }   // B2-of-t landed
    BAR;

    // ---- P1: frags B2 k0; MFMA acc2 k0 ----
#pragma unroll
    for (int n = 0; n < 4; ++n) bf_[n] = *(const bf16x8*)(B2b + rboff[n]);
    BAR;
    __builtin_amdgcn_s_setprio(1);
#pragma unroll
    for (int m = 0; m < 4; ++m)
#pragma unroll
      for (int n = 0; n < 4; ++n)
        acc2[m][n] = __builtin_amdgcn_mfma_f32_16x16x32_bf16(af[m], bf_[n], acc2[m][n], 0, 0, 0);
    __builtin_amdgcn_s_setprio(0);
    BAR;

    // ---- P2: frags A k1 + B1 k1; MFMA acc1 k1 ----
#pragma unroll
    for (int m = 0; m < 4; ++m) af[m] = *(const bf16x8*)(Ab + (raoff[m] ^ 32));
#pragma unroll
    for (int n = 0; n < 4; ++n) bf_[n] = *(const bf16x8*)(B1b + (rboff[n] ^ 32));
    BAR;
    __builtin_amdgcn_s_setprio(1);
#pragma unroll
    for (int m = 0; m < 4; ++m)
#pragma unroll
      for (int n = 0; n < 4; ++n)
        acc1[m][n] = __builtin_amdgcn_mfma_f32_16x16x32_bf16(af[m], bf_[n], acc1[m][n], 0, 0, 0);
    __builtin_amdgcn_s_setprio(0);
    BAR;

    // ---- P3: frags B2 k1; MFMA acc2 k1; wait rounds 0-5 of t+1 ----
#pragma unroll
    for (int n = 0; n < 4; ++n) bf_[n] = *(const bf16x8*)(B2b + (rboff[n] ^ 32));
    BAR;
    __builtin_amdgcn_s_setprio(1);
#pragma unroll
    for (int m = 0; m < 4; ++m)
#pragma unroll
      for (int n = 0; n < 4; ++n)
        acc2[m][n] = __builtin_amdgcn_mfma_f32_16x16x32_bf16(af[m], bf_[n], acc2[m][n], 0, 0, 0);
    __builtin_amdgcn_s_setprio(0);
    if (pf) { VMCNT2; }
    BAR;
  }

  // epilogue: h = silu(x1)*x2, bf16
#pragma unroll
  for (int m = 0; m < 4; ++m)
#pragma unroll
    for (int n = 0; n < 4; ++n)
#pragma unroll
      for (int r = 0; r < 4; ++r) {
        int row = m0 + wm * 64 + m * 16 + kq * 4 + r;
        int col = n0 + wn * 64 + n * 16 + lr;
        float x1 = acc1[m][n][r], x2 = acc2[m][n][r];
        float hv = x1 / (1.f + __expf(-x1)) * x2;
        Hb[(long)row * FFN_DIM + col] = f2bf(hv);
      }
#undef ST_A
#undef ST_B1
#undef ST_B2
}

// ---------- GEMM2, 2-phase, triple-buffered, prefetch distance 2 ----------
// tile 256(m) x 128(n), BK=64, 8 waves (4M x 2N), per-wave 64x64.
// LDS: A 3x(256x64) + B 3x(128x64) bf16 = 144 KiB. grid=256 = 1 block/CU.
// Per tile: P0 issues all 6 rounds for t+2; single vmcnt(6) at end-P1
// covers loads issued 4 phases earlier.
__global__ __launch_bounds__(512, 2) void gemm2(
    const unsigned short* __restrict__ Hb,    // (4096,8192)
    const unsigned short* __restrict__ W2T,   // (2048,8192)
    float* __restrict__ out) {                // (4096,2048)
  __shared__ __align__(16) unsigned short sA[3 * 256 * 64];
  __shared__ __align__(16) unsigned short sB[3 * 128 * 64];

  const int tid = threadIdx.x;
  const int wv = tid >> 6, l = tid & 63;
  const int wm = wv >> 1, wn = wv & 1;
  const int kq = l >> 4, lr = l & 15;
  const int m0 = blockIdx.y << 8;   // T/256 = 16
  const int n0 = blockIdx.x << 7;   // D/128 = 16

  const int rsub = tid >> 3;
  const int sslot8 = ((tid & 7) ^ ((tid >> 3) & 7)) << 3;
  const unsigned short* gA0  = Hb  + (long)(m0 + rsub) * FFN_DIM + sslot8;
  const unsigned short* gB0r = W2T + (long)(n0 + rsub) * FFN_DIM + sslot8;

#define ST2_A(r_) gload16(gA0  + (long)((r_) * 64) * FFN_DIM + tc2, sA + bwr * 16384 + (r_) * 4096 + wv * 512)
#define ST2_B(r_) gload16(gB0r + (long)((r_) * 64) * FFN_DIM + tc2, sB + bwr * 8192  + (r_) * 4096 + wv * 512)

  int raoff[4], rboff[4];
#pragma unroll
  for (int m = 0; m < 4; ++m) {
    int row = wm * 64 + m * 16 + lr;
    raoff[m] = row * 64 + ((kq ^ (row & 7)) << 3);
  }
#pragma unroll
  for (int n = 0; n < 4; ++n) {
    int row = wn * 64 + n * 16 + lr;
    rboff[n] = row * 64 + ((kq ^ (row & 7)) << 3);
  }

  f32x4 acc[4][4];
  f32x4 z = {0.f, 0.f, 0.f, 0.f};
#pragma unroll
  for (int m = 0; m < 4; ++m)
#pragma unroll
    for (int n = 0; n < 4; ++n) acc[m][n] = z;

  // prologue: stage tiles 0 and 1; wait tile 0 (6 of tile-1 stay outstanding)
  {
    int tc2 = 0, bwr = 0;
    ST2_A(0); ST2_A(1); ST2_A(2); ST2_A(3); ST2_B(0); ST2_B(1);
    tc2 = 64; bwr = 1;
    ST2_A(0); ST2_A(1); ST2_A(2); ST2_A(3); ST2_B(0); ST2_B(1);
    VMCNT6;
    BAR;
  }

  const int NT = FFN_DIM / 64;  // 128
  int brd = 0;
  for (int t = 0; t < NT; ++t) {
    const unsigned short* Ab = sA + brd * 16384;
    const unsigned short* Bb = sB + brd * 8192;
    const int pf2 = (t + 2 < NT);
    const int tc2 = (t + 2) << 6;
    const int bwr = (brd + 2 >= 3) ? brd - 1 : brd + 2;
    bf16x8 af[4], bf_[4];

    // ---- P0: frags k0; issue all 6 rounds for t+2; MFMA k0 ----
#pragma unroll
    for (int m = 0; m < 4; ++m) af[m] = *(const bf16x8*)(Ab + raoff[m]);
#pragma unroll
    for (int n = 0; n < 4; ++n) bf_[n] = *(const bf16x8*)(Bb + rboff[n]);
    if (pf2) {
      ST2_A(0); ST2_A(1); ST2_A(2); ST2_A(3); ST2_B(0); ST2_B(1);
    }
    BAR;
    __builtin_amdgcn_s_setprio(1);
#pragma unroll
    for (int m = 0; m < 4; ++m)
#pragma unroll
      for (int n = 0; n < 4; ++n)
        acc[m][n] = __builtin_amdgcn_mfma_f32_16x16x32_bf16(af[m], bf_[n], acc[m][n], 0, 0, 0);
    __builtin_amdgcn_s_setprio(0);
    BAR;

    // ---- P1: frags k1; MFMA k1; wait tile t+1's rounds ----
#pragma unroll
    for (int m = 0; m < 4; ++m) af[m] = *(const bf16x8*)(Ab + (raoff[m] ^ 32));
#pragma unroll
    for (int n = 0; n < 4; ++n) bf_[n] = *(const bf16x8*)(Bb + (rboff[n] ^ 32));
    BAR;
    __builtin_amdgcn_s_setprio(1);
#pragma unroll
    for (int m = 0; m < 4; ++m)
#pragma unroll
      for (int n = 0; n < 4; ++n)
        acc[m][n] = __builtin_amdgcn_mfma_f32_16x16x32_bf16(af[m], bf_[n], acc[m][n], 0, 0, 0);
    __builtin_amdgcn_s_setprio(0);
    if (pf2) { VMCNT6; } else if (t + 1 < NT) { VMCNT0; }
    BAR;

    brd = (brd + 1 == 3) ? 0 : brd + 1;
  }

#pragma unroll
  for (int m = 0; m < 4; ++m)
#pragma unroll
    for (int n = 0; n < 4; ++n)
#pragma unroll
      for (int r = 0; r < 4; ++r) {
        int row = m0 + wm * 64 + m * 16 + kq * 4 + r;
        int col = n0 + wn * 64 + n * 16 + lr;
        out[(long)row * D_DIM + col] = acc[m][n][r];
      }
#undef ST2_A
#undef ST2_B
}

extern "C" void kernel_launch(void* const* d_in, const int* in_sizes, int n_in,
                              void* d_out, int out_size, void* d_ws, size_t ws_size,
                              hipStream_t stream) {
  const float* x  = (const float*)d_in[0];
  const float* w1 = (const float*)d_in[1];
  const float* v1 = (const float*)d_in[2];
  const float* w2 = (const float*)d_in[3];
  const int* eidx = (const int*)d_in[4];

  char* ws = (char*)d_ws;
  unsigned short* Xb  = (unsigned short*)(ws);                  // 16 MiB
  unsigned short* W1b = (unsigned short*)(ws + (16l << 20));    // 32 MiB
  unsigned short* V1b = (unsigned short*)(ws + (48l << 20));    // 32 MiB
  unsigned short* W2T = (unsigned short*)(ws + (80l << 20));    // 32 MiB
  unsigned short* Hb  = (unsigned short*)(ws + (112l << 20));   // 64 MiB
  float* out = (float*)d_out;

  long slab = (long)FFN_DIM * D_DIM;
  convert_kernel<<<2048, 256, 0, stream>>>(x,  eidx, 0,    Xb,  (long)T_DIM * D_DIM);
  convert_kernel<<<2048, 256, 0, stream>>>(w1, eidx, slab, W1b, slab);
  convert_kernel<<<2048, 256, 0, stream>>>(v1, eidx, slab, V1b, slab);
  transpose_kernel<<<dim3(D_DIM / 32, FFN_DIM / 32), 256, 0, stream>>>(w2, eidx, W2T);
  gemm1_silu<<<dim3(FFN_DIM / 128, T_DIM / 256), 512, 0, stream>>>(Xb, W1b, V1b, Hb);
  gemm2<<<dim3(D_DIM / 128, T_DIM / 256), 512, 0, stream>>>(Hb, W2T, out);
}

// Round 5
// 491.556 us; speedup vs baseline: 1.0952x; 1.0952x over previous
//
#include <hip/hip_runtime.h>

#define E_NUM 8
#define FFN_DIM 8192
#define D_DIM 2048
#define T_DIM 4096

using bf16x8 = __attribute__((ext_vector_type(8))) short;
using f32x4  = __attribute__((ext_vector_type(4))) float;
using u16x8  = __attribute__((ext_vector_type(8))) unsigned short;

__device__ __forceinline__ unsigned short f2bf(float f) {
  union { float f; unsigned int u; } v; v.f = f;
  unsigned int u = v.u;
  unsigned int r = (u + 0x7FFFu + ((u >> 16) & 1u)) >> 16;
  return (unsigned short)r;
}

__device__ __forceinline__ void gload16(const unsigned short* g, const unsigned short* l) {
  __builtin_amdgcn_global_load_lds(
      (const __attribute__((address_space(1))) void*)g,
      (__attribute__((address_space(3))) void*)l, 16, 0, 0);
}

// ---------- prep: fp32 -> bf16 convert ----------
__global__ void convert_kernel(const float* __restrict__ src_base,
                               const int* __restrict__ eidx, long slab,
                               unsigned short* __restrict__ dst, long n) {
  const float* src = src_base + (long)(*eidx) * slab;
  long stride = (long)gridDim.x * blockDim.x;
  for (long i = (long)blockIdx.x * blockDim.x + threadIdx.x; i * 8 < n; i += stride) {
    long e = i * 8;
    const float4* p = (const float4*)(src + e);
    float4 f0 = p[0], f1 = p[1];
    u16x8 o;
    o[0] = f2bf(f0.x); o[1] = f2bf(f0.y); o[2] = f2bf(f0.z); o[3] = f2bf(f0.w);
    o[4] = f2bf(f1.x); o[5] = f2bf(f1.y); o[6] = f2bf(f1.z); o[7] = f2bf(f1.w);
    *(u16x8*)(dst + e) = o;
  }
}

// ---------- prep: transpose w2 slab (FFN,D) fp32 -> (D,FFN) bf16 ----------
__global__ void transpose_kernel(const float* __restrict__ w2,
                                 const int* __restrict__ eidx,
                                 unsigned short* __restrict__ dst) {
  __shared__ unsigned short tile[32][33];
  const float* src = w2 + (long)(*eidx) * (long)FFN_DIM * D_DIM;
  int d0 = blockIdx.x << 5;
  int f0 = blockIdx.y << 5;
  int tx = threadIdx.x & 31, ty = threadIdx.x >> 5;
#pragma unroll
  for (int i = 0; i < 4; ++i) {
    int f = ty + i * 8;
    tile[f][tx] = f2bf(src[(long)(f0 + f) * D_DIM + d0 + tx]);
  }
  __syncthreads();
#pragma unroll
  for (int i = 0; i < 4; ++i) {
    int d = ty + i * 8;
    dst[(long)(d0 + d) * FFN_DIM + f0 + tx] = tile[tx][d];
  }
}

#define VMCNT6 asm volatile("s_waitcnt vmcnt(6)" ::: "memory")
#define VMCNT4 asm volatile("s_waitcnt vmcnt(4)" ::: "memory")
#define VMCNT0 asm volatile("s_waitcnt vmcnt(0)" ::: "memory")
#define BAR __builtin_amdgcn_s_barrier()
#define PRIO1 __builtin_amdgcn_s_setprio(1)
#define PRIO0 __builtin_amdgcn_s_setprio(0)

// ---------- GEMM1 fused: region-confined 4-phase schedule ----------
// tile 256m x 128n(dual), BK=64, 8 waves 2Mx4N, per-wave 128x32 per GEMM.
// LDS regions/tile: A0,A1 (128x64 halves), B1, B2 (128x64 each) = 64KB x2 dbuf.
// Reads confined: p1:{A0,B1} p2:{A1} p3:{B2} p4:{} (reg-cached reuse).
// Stages: p1:(t+1)B2[other dbuf]  p2:(t+2)A0  p3:(t+2)A1  p4:(t+2)B1 [curr dbuf,
//   each after its region's last read + barrier => WAR-safe].
// One vmcnt(6) at p4 drains exactly tile t+1 (keeps 3 newest halves in flight).
__global__ __launch_bounds__(512, 2) void gemm1_silu(
    const unsigned short* __restrict__ Xb,    // (4096,2048)
    const unsigned short* __restrict__ W1b,   // (8192,2048)
    const unsigned short* __restrict__ V1b,   // (8192,2048)
    unsigned short* __restrict__ Hb) {        // (4096,8192)
  __shared__ __align__(16) unsigned short sA[2 * 2 * 8192];   // [dbuf][half][128*64]
  __shared__ __align__(16) unsigned short sB1[2 * 8192];
  __shared__ __align__(16) unsigned short sB2[2 * 8192];

  const int tid = threadIdx.x;
  const int wv = tid >> 6, l = tid & 63;
  const int wm = wv >> 2, wn = wv & 3;        // 2M x 4N
  const int kq = l >> 4, lr = l & 15;
  const int m0 = blockIdx.y << 8;
  const int n0 = blockIdx.x << 7;

  const int rsub = tid >> 3;
  const int sslot8 = ((tid & 7) ^ ((tid >> 3) & 7)) << 3;
  const unsigned short* gA  = Xb  + (long)(m0 + rsub) * D_DIM + sslot8;
  const unsigned short* gB1 = W1b + (long)(n0 + rsub) * D_DIM + sslot8;
  const unsigned short* gB2 = V1b + (long)(n0 + rsub) * D_DIM + sslot8;

  // stage one 128x64 half (2 gload rounds)
#define STG(gbase, rowoff, tc_, lbase) do { \
    gload16((gbase) + (long)(rowoff) * D_DIM + (tc_), (lbase) + wv * 512); \
    gload16((gbase) + (long)((rowoff) + 64) * D_DIM + (tc_), (lbase) + 4096 + wv * 512); \
  } while (0)

  int aoff[4], boff[2];
#pragma unroll
  for (int j = 0; j < 4; ++j) {
    int row = wm * 64 + j * 16 + lr;
    aoff[j] = row * 64 + ((kq ^ (row & 7)) << 3);
  }
#pragma unroll
  for (int g = 0; g < 2; ++g) {
    int row = wn * 32 + g * 16 + lr;
    boff[g] = row * 64 + ((kq ^ (row & 7)) << 3);
  }

  f32x4 acc1[8][2], acc2[8][2];
  f32x4 z = {0.f, 0.f, 0.f, 0.f};
#pragma unroll
  for (int f = 0; f < 8; ++f)
#pragma unroll
    for (int g = 0; g < 2; ++g) { acc1[f][g] = z; acc2[f][g] = z; }

  // prologue: t0 fully, t1 {A0,A1,B1}; keep 3 newest halves in flight
  STG(gA, 0, 0, sA);                 // t0 A0 (dbuf0)
  STG(gA, 128, 0, sA + 8192);        // t0 A1
  STG(gB1, 0, 0, sB1);               // t0 B1
  STG(gB2, 0, 0, sB2);               // t0 B2
  STG(gA, 0, 64, sA + 16384);        // t1 A0 (dbuf1)
  STG(gA, 128, 64, sA + 24576);      // t1 A1
  STG(gB1, 0, 64, sB1 + 8192);       // t1 B1
  VMCNT6;
  BAR;

  const int NT = D_DIM / 64;  // 32
  for (int t = 0; t < NT; ++t) {
    const int db = t & 1, sx = db ^ 1;
    const unsigned short* A0p = sA + (db * 2 + 0) * 8192;
    const unsigned short* A1p = sA + (db * 2 + 1) * 8192;
    const unsigned short* B1p = sB1 + db * 8192;
    const unsigned short* B2p = sB2 + db * 8192;
    const int p1ok = (t + 1 < NT), p2ok = (t + 2 < NT);
    const int tc1 = (t + 1) << 6, tc2 = (t + 2) << 6;
    bf16x8 aA[4][2], aB[4][2], b1[2][2], b2[2][2];

    // ---- P1: read A0+B1 frags; stage (t+1)B2; MFMA acc1 mh0 ----
#pragma unroll
    for (int j = 0; j < 4; ++j) {
      aA[j][0] = *(const bf16x8*)(A0p + aoff[j]);
      aA[j][1] = *(const bf16x8*)(A0p + (aoff[j] ^ 32));
    }
#pragma unroll
    for (int g = 0; g < 2; ++g) {
      b1[g][0] = *(const bf16x8*)(B1p + boff[g]);
      b1[g][1] = *(const bf16x8*)(B1p + (boff[g] ^ 32));
    }
    if (p1ok) STG(gB2, 0, tc1, sB2 + sx * 8192);
    BAR;
    PRIO1;
#pragma unroll
    for (int j = 0; j < 4; ++j)
#pragma unroll
      for (int g = 0; g < 2; ++g) {
        acc1[j][g] = __builtin_amdgcn_mfma_f32_16x16x32_bf16(aA[j][0], b1[g][0], acc1[j][g], 0, 0, 0);
        acc1[j][g] = __builtin_amdgcn_mfma_f32_16x16x32_bf16(aA[j][1], b1[g][1], acc1[j][g], 0, 0, 0);
      }
    PRIO0;
    BAR;

    // ---- P2: read A1 frags; stage (t+2)A0; MFMA acc1 mh1 ----
#pragma unroll
    for (int j = 0; j < 4; ++j) {
      aB[j][0] = *(const bf16x8*)(A1p + aoff[j]);
      aB[j][1] = *(const bf16x8*)(A1p + (aoff[j] ^ 32));
    }
    if (p2ok) STG(gA, 0, tc2, sA + (db * 2 + 0) * 8192);
    BAR;
    PRIO1;
#pragma unroll
    for (int j = 0; j < 4; ++j)
#pragma unroll
      for (int g = 0; g < 2; ++g) {
        acc1[4 + j][g] = __builtin_amdgcn_mfma_f32_16x16x32_bf16(aB[j][0], b1[g][0], acc1[4 + j][g], 0, 0, 0);
        acc1[4 + j][g] = __builtin_amdgcn_mfma_f32_16x16x32_bf16(aB[j][1], b1[g][1], acc1[4 + j][g], 0, 0, 0);
      }
    PRIO0;
    BAR;

    // ---- P3: read B2 frags; stage (t+2)A1; MFMA acc2 mh0 ----
#pragma unroll
    for (int g = 0; g < 2; ++g) {
      b2[g][0] = *(const bf16x8*)(B2p + boff[g]);
      b2[g][1] = *(const bf16x8*)(B2p + (boff[g] ^ 32));
    }
    if (p2ok) STG(gA, 128, tc2, sA + (db * 2 + 1) * 8192);
    BAR;
    PRIO1;
#pragma unroll
    for (int j = 0; j < 4; ++j)
#pragma unroll
      for (int g = 0; g < 2; ++g) {
        acc2[j][g] = __builtin_amdgcn_mfma_f32_16x16x32_bf16(aA[j][0], b2[g][0], acc2[j][g], 0, 0, 0);
        acc2[j][g] = __builtin_amdgcn_mfma_f32_16x16x32_bf16(aA[j][1], b2[g][1], acc2[j][g], 0, 0, 0);
      }
    PRIO0;
    BAR;

    // ---- P4: stage (t+2)B1; MFMA acc2 mh1 (all regs); counted wait ----
    if (p2ok) STG(gB1, 0, tc2, sB1 + db * 8192);
    BAR;
    PRIO1;
#pragma unroll
    for (int j = 0; j < 4; ++j)
#pragma unroll
      for (int g = 0; g < 2; ++g) {
        acc2[4 + j][g] = __builtin_amdgcn_mfma_f32_16x16x32_bf16(aB[j][0], b2[g][0], acc2[4 + j][g], 0, 0, 0);
        acc2[4 + j][g] = __builtin_amdgcn_mfma_f32_16x16x32_bf16(aB[j][1], b2[g][1], acc2[4 + j][g], 0, 0, 0);
      }
    PRIO0;
    if (p2ok) { VMCNT6; } else if (p1ok) { VMCNT0; }
    BAR;
  }

  // epilogue: h = silu(x1)*x2, bf16
#pragma unroll
  for (int f = 0; f < 8; ++f)
#pragma unroll
    for (int g = 0; g < 2; ++g)
#pragma unroll
      for (int r = 0; r < 4; ++r) {
        int row = m0 + (f >> 2) * 128 + wm * 64 + (f & 3) * 16 + kq * 4 + r;
        int col = n0 + wn * 32 + g * 16 + lr;
        float x1 = acc1[f][g][r], x2 = acc2[f][g][r];
        float hv = x1 / (1.f + __expf(-x1)) * x2;
        Hb[(long)row * FFN_DIM + col] = f2bf(hv);
      }
#undef STG
}

// ---------- GEMM2: same region-confined schedule, single B ----------
// tile 256m x 128n, BK=64, 8 waves 4Mx2N, per-wave 64x64.
// Regions/tile: A0,A1,B. Reads: p1:{A f01, B g01} p2:{A f23} p3:{B g23} p4:{}.
// Stages: p1:(t+1)B  p3:(t+2)A0  p4:(t+2)A1. vmcnt(4) at p4.
__global__ __launch_bounds__(512, 2) void gemm2(
    const unsigned short* __restrict__ Hb,    // (4096,8192)
    const unsigned short* __restrict__ W2T,   // (2048,8192)
    float* __restrict__ out) {                // (4096,2048)
  __shared__ __align__(16) unsigned short sA[2 * 2 * 8192];
  __shared__ __align__(16) unsigned short sB[2 * 8192];

  const int tid = threadIdx.x;
  const int wv = tid >> 6, l = tid & 63;
  const int wm = wv >> 1, wn = wv & 1;        // 4M x 2N
  const int kq = l >> 4, lr = l & 15;
  const int m0 = blockIdx.y << 8;             // T/256 = 16
  const int n0 = blockIdx.x << 7;             // D/128 = 16
  const int hA = wm >> 1;

  const int rsub = tid >> 3;
  const int sslot8 = ((tid & 7) ^ ((tid >> 3) & 7)) << 3;
  const unsigned short* gA = Hb  + (long)(m0 + rsub) * FFN_DIM + sslot8;
  const unsigned short* gB = W2T + (long)(n0 + rsub) * FFN_DIM + sslot8;

#define STG2(gbase, rowoff, tc_, lbase) do { \
    gload16((gbase) + (long)(rowoff) * FFN_DIM + (tc_), (lbase) + wv * 512); \
    gload16((gbase) + (long)((rowoff) + 64) * FFN_DIM + (tc_), (lbase) + 4096 + wv * 512); \
  } while (0)

  int aoff[4], boff[4];
#pragma unroll
  for (int f = 0; f < 4; ++f) {
    int row = (wm & 1) * 64 + f * 16 + lr;     // within A-half hA
    aoff[f] = row * 64 + ((kq ^ (row & 7)) << 3);
  }
#pragma unroll
  for (int g = 0; g < 4; ++g) {
    int row = wn * 64 + g * 16 + lr;
    boff[g] = row * 64 + ((kq ^ (row & 7)) << 3);
  }

  f32x4 acc[4][4];
  f32x4 z = {0.f, 0.f, 0.f, 0.f};
#pragma unroll
  for (int f = 0; f < 4; ++f)
#pragma unroll
    for (int g = 0; g < 4; ++g) acc[f][g] = z;

  // prologue: t0 {A0,A1,B}, t1 {A0,A1}; keep 2 newest halves in flight
  STG2(gA, 0, 0, sA);
  STG2(gA, 128, 0, sA + 8192);
  STG2(gB, 0, 0, sB);
  STG2(gA, 0, 64, sA + 16384);
  STG2(gA, 128, 64, sA + 24576);
  VMCNT4;
  BAR;

  const int NT = FFN_DIM / 64;  // 128
  for (int t = 0; t < NT; ++t) {
    const int db = t & 1, sx = db ^ 1;
    const unsigned short* Ap = sA + (db * 2 + hA) * 8192;
    const unsigned short* Bp = sB + db * 8192;
    const int p1ok = (t + 1 < NT), p2ok = (t + 2 < NT);
    const int tc1 = (t + 1) << 6, tc2 = (t + 2) << 6;
    bf16x8 aA[2][2], aB[2][2], bA[2][2], bB[2][2];

    // ---- P1: read A f01 + B g01; stage (t+1)B; MFMA f01xg01 ----
#pragma unroll
    for (int f = 0; f < 2; ++f) {
      aA[f][0] = *(const bf16x8*)(Ap + aoff[f]);
      aA[f][1] = *(const bf16x8*)(Ap + (aoff[f] ^ 32));
    }
#pragma unroll
    for (int g = 0; g < 2; ++g) {
      bA[g][0] = *(const bf16x8*)(Bp + boff[g]);
      bA[g][1] = *(const bf16x8*)(Bp + (boff[g] ^ 32));
    }
    if (p1ok) STG2(gB, 0, tc1, sB + sx * 8192);
    BAR;
    PRIO1;
#pragma unroll
    for (int f = 0; f < 2; ++f)
#pragma unroll
      for (int g = 0; g < 2; ++g) {
        acc[f][g] = __builtin_amdgcn_mfma_f32_16x16x32_bf16(aA[f][0], bA[g][0], acc[f][g], 0, 0, 0);
        acc[f][g] = __builtin_amdgcn_mfma_f32_16x16x32_bf16(aA[f][1], bA[g][1], acc[f][g], 0, 0, 0);
      }
    PRIO0;
    BAR;

    // ---- P2: read A f23; MFMA f23xg01 ----
#pragma unroll
    for (int f = 0; f < 2; ++f) {
      aB[f][0] = *(const bf16x8*)(Ap + aoff[2 + f]);
      aB[f][1] = *(const bf16x8*)(Ap + (aoff[2 + f] ^ 32));
    }
    BAR;
    PRIO1;
#pragma unroll
    for (int f = 0; f < 2; ++f)
#pragma unroll
      for (int g = 0; g < 2; ++g) {
        acc[2 + f][g] = __builtin_amdgcn_mfma_f32_16x16x32_bf16(aB[f][0], bA[g][0], acc[2 + f][g], 0, 0, 0);
        acc[2 + f][g] = __builtin_amdgcn_mfma_f32_16x16x32_bf16(aB[f][1], bA[g][1], acc[2 + f][g], 0, 0, 0);
      }
    PRIO0;
    BAR;

    // ---- P3: read B g23; stage (t+2)A0; MFMA f01xg23 ----
#pragma unroll
    for (int g = 0; g < 2; ++g) {
      bB[g][0] = *(const bf16x8*)(Bp + boff[2 + g]);
      bB[g][1] = *(const bf16x8*)(Bp + (boff[2 + g] ^ 32));
    }
    if (p2ok) STG2(gA, 0, tc2, sA + (db * 2 + 0) * 8192);
    BAR;
    PRIO1;
#pragma unroll
    for (int f = 0; f < 2; ++f)
#pragma unroll
      for (int g = 0; g < 2; ++g) {
        acc[f][2 + g] = __builtin_amdgcn_mfma_f32_16x16x32_bf16(aA[f][0], bB[g][0], acc[f][2 + g], 0, 0, 0);
        acc[f][2 + g] = __builtin_amdgcn_mfma_f32_16x16x32_bf16(aA[f][1], bB[g][1], acc[f][2 + g], 0, 0, 0);
      }
    PRIO0;
    BAR;

    // ---- P4: stage (t+2)A1; MFMA f23xg23 (all regs); counted wait ----
    if (p2ok) STG2(gA, 128, tc2, sA + (db * 2 + 1) * 8192);
    BAR;
    PRIO1;
#pragma unroll
    for (int f = 0; f < 2; ++f)
#pragma unroll
      for (int g = 0; g < 2; ++g) {
        acc[2 + f][2 + g] = __builtin_amdgcn_mfma_f32_16x16x32_bf16(aB[f][0], bB[g][0], acc[2 + f][2 + g], 0, 0, 0);
        acc[2 + f][2 + g] = __builtin_amdgcn_mfma_f32_16x16x32_bf16(aB[f][1], bB[g][1], acc[2 + f][2 + g], 0, 0, 0);
      }
    PRIO0;
    if (p2ok) { VMCNT4; } else if (p1ok) { VMCNT0; }
    BAR;
  }

#pragma unroll
  for (int f = 0; f < 4; ++f)
#pragma unroll
    for (int g = 0; g < 4; ++g)
#pragma unroll
      for (int r = 0; r < 4; ++r) {
        int row = m0 + wm * 64 + f * 16 + kq * 4 + r;
        int col = n0 + wn * 64 + g * 16 + lr;
        out[(long)row * D_DIM + col] = acc[f][g][r];
      }
#undef STG2
}

extern "C" void kernel_launch(void* const* d_in, const int* in_sizes, int n_in,
                              void* d_out, int out_size, void* d_ws, size_t ws_size,
                              hipStream_t stream) {
  const float* x  = (const float*)d_in[0];
  const float* w1 = (const float*)d_in[1];
  const float* v1 = (const float*)d_in[2];
  const float* w2 = (const float*)d_in[3];
  const int* eidx = (const int*)d_in[4];

  char* ws = (char*)d_ws;
  unsigned short* Xb  = (unsigned short*)(ws);                  // 16 MiB
  unsigned short* W1b = (unsigned short*)(ws + (16l << 20));    // 32 MiB
  unsigned short* V1b = (unsigned short*)(ws + (48l << 20));    // 32 MiB
  unsigned short* W2T = (unsigned short*)(ws + (80l << 20));    // 32 MiB
  unsigned short* Hb  = (unsigned short*)(ws + (112l << 20));   // 64 MiB
  float* out = (float*)d_out;

  long slab = (long)FFN_DIM * D_DIM;
  convert_kernel<<<2048, 256, 0, stream>>>(x,  eidx, 0,    Xb,  (long)T_DIM * D_DIM);
  convert_kernel<<<2048, 256, 0, stream>>>(w1, eidx, slab, W1b, slab);
  convert_kernel<<<2048, 256, 0, stream>>>(v1, eidx, slab, V1b, slab);
  transpose_kernel<<<dim3(D_DIM / 32, FFN_DIM / 32), 256, 0, stream>>>(w2, eidx, W2T);
  gemm1_silu<<<dim3(FFN_DIM / 128, T_DIM / 256), 512, 0, stream>>>(Xb, W1b, V1b, Hb);
  gemm2<<<dim3(D_DIM / 128, T_DIM / 256), 512, 0, stream>>>(Hb, W2T, out);
}

// Round 6
// 490.592 us; speedup vs baseline: 1.0974x; 1.0020x over previous
//
#include <hip/hip_runtime.h>

#define E_NUM 8
#define FFN_DIM 8192
#define D_DIM 2048
#define T_DIM 4096

using bf16x8 = __attribute__((ext_vector_type(8))) short;
using f32x4  = __attribute__((ext_vector_type(4))) float;
using u16x8  = __attribute__((ext_vector_type(8))) unsigned short;

__device__ __forceinline__ unsigned short f2bf(float f) {
  union { float f; unsigned int u; } v; v.f = f;
  unsigned int u = v.u;
  unsigned int r = (u + 0x7FFFu + ((u >> 16) & 1u)) >> 16;
  return (unsigned short)r;
}

__device__ __forceinline__ void gload16(const unsigned short* g, const unsigned short* l) {
  __builtin_amdgcn_global_load_lds(
      (const __attribute__((address_space(1))) void*)g,
      (__attribute__((address_space(3))) void*)l, 16, 0, 0);
}

// ---------- prep: fp32 -> bf16 convert ----------
__global__ void convert_kernel(const float* __restrict__ src_base,
                               const int* __restrict__ eidx, long slab,
                               unsigned short* __restrict__ dst, long n) {
  const float* src = src_base + (long)(*eidx) * slab;
  long stride = (long)gridDim.x * blockDim.x;
  for (long i = (long)blockIdx.x * blockDim.x + threadIdx.x; i * 8 < n; i += stride) {
    long e = i * 8;
    const float4* p = (const float4*)(src + e);
    float4 f0 = p[0], f1 = p[1];
    u16x8 o;
    o[0] = f2bf(f0.x); o[1] = f2bf(f0.y); o[2] = f2bf(f0.z); o[3] = f2bf(f0.w);
    o[4] = f2bf(f1.x); o[5] = f2bf(f1.y); o[6] = f2bf(f1.z); o[7] = f2bf(f1.w);
    *(u16x8*)(dst + e) = o;
  }
}

// ---------- prep: transpose w2 slab (FFN,D) fp32 -> (D,FFN) bf16 ----------
__global__ void transpose_kernel(const float* __restrict__ w2,
                                 const int* __restrict__ eidx,
                                 unsigned short* __restrict__ dst) {
  __shared__ unsigned short tile[32][33];
  const float* src = w2 + (long)(*eidx) * (long)FFN_DIM * D_DIM;
  int d0 = blockIdx.x << 5;
  int f0 = blockIdx.y << 5;
  int tx = threadIdx.x & 31, ty = threadIdx.x >> 5;
#pragma unroll
  for (int i = 0; i < 4; ++i) {
    int f = ty + i * 8;
    tile[f][tx] = f2bf(src[(long)(f0 + f) * D_DIM + d0 + tx]);
  }
  __syncthreads();
#pragma unroll
  for (int i = 0; i < 4; ++i) {
    int d = ty + i * 8;
    dst[(long)(d0 + d) * FFN_DIM + f0 + tx] = tile[tx][d];
  }
}

#define VMCNT8 asm volatile("s_waitcnt vmcnt(8)" ::: "memory")
#define VMCNT6 asm volatile("s_waitcnt vmcnt(6)" ::: "memory")
#define VMCNT0 asm volatile("s_waitcnt vmcnt(0)" ::: "memory")
#define BAR __builtin_amdgcn_s_barrier()
#define PRIO1 __builtin_amdgcn_s_setprio(1)
#define PRIO0 __builtin_amdgcn_s_setprio(0)

// ---------- GEMM1 fused: region-confined 4-phase, prefetch t+2, XCD swizzle ----
// tile 256m x 128n(dual), BK=64, 8 waves 2Mx4N.
// Reads confined: p1:{A0,B1} p2:{A1} p3:{B2} p4:{}.
// Stages (all for tile t+2, own dbuf, after region's last read):
//   p2:{A0,B1} p3:{A1} p4:{B2}; vmcnt(8) at p4 keeps exactly t+2 in flight
//   => every load has 4-6 phases of cover.
// Grid: 1024 blocks 1D; XCD-chunked bijective swizzle, m-fastest within XCD
// (one B-panel L2-resident per XCD while A sweeps L3).
__global__ __launch_bounds__(512, 2) void gemm1_silu(
    const unsigned short* __restrict__ Xb,    // (4096,2048)
    const unsigned short* __restrict__ W1b,   // (8192,2048)
    const unsigned short* __restrict__ V1b,   // (8192,2048)
    unsigned short* __restrict__ Hb) {        // (4096,8192)
  __shared__ __align__(16) unsigned short sA[2 * 2 * 8192];   // [dbuf][half][128*64]
  __shared__ __align__(16) unsigned short sB1[2 * 8192];
  __shared__ __align__(16) unsigned short sB2[2 * 8192];

  const int tid = threadIdx.x;
  const int wv = tid >> 6, l = tid & 63;
  const int wm = wv >> 2, wn = wv & 3;        // 2M x 4N
  const int kq = l >> 4, lr = l & 15;
  // XCD-chunked swizzle: 1024 wg, 128/XCD contiguous, m-fastest (16 m-blocks)
  const int bsw = (blockIdx.x & 7) * 128 + (blockIdx.x >> 3);
  const int m0 = (bsw & 15) << 8;
  const int n0 = (bsw >> 4) << 7;

  const int rsub = tid >> 3;
  const int sslot8 = ((tid & 7) ^ ((tid >> 3) & 7)) << 3;
  const unsigned short* gA  = Xb  + (long)(m0 + rsub) * D_DIM + sslot8;
  const unsigned short* gB1 = W1b + (long)(n0 + rsub) * D_DIM + sslot8;
  const unsigned short* gB2 = V1b + (long)(n0 + rsub) * D_DIM + sslot8;

#define STG(gbase, rowoff, tc_, lbase) do { \
    gload16((gbase) + (long)(rowoff) * D_DIM + (tc_), (lbase) + wv * 512); \
    gload16((gbase) + (long)((rowoff) + 64) * D_DIM + (tc_), (lbase) + 4096 + wv * 512); \
  } while (0)

  int aoff[4], boff[2];
#pragma unroll
  for (int j = 0; j < 4; ++j) {
    int row = wm * 64 + j * 16 + lr;
    aoff[j] = row * 64 + ((kq ^ (row & 7)) << 3);
  }
#pragma unroll
  for (int g = 0; g < 2; ++g) {
    int row = wn * 32 + g * 16 + lr;
    boff[g] = row * 64 + ((kq ^ (row & 7)) << 3);
  }

  f32x4 acc1[8][2], acc2[8][2];
  f32x4 z = {0.f, 0.f, 0.f, 0.f};
#pragma unroll
  for (int f = 0; f < 8; ++f)
#pragma unroll
    for (int g = 0; g < 2; ++g) { acc1[f][g] = z; acc2[f][g] = z; }

  // prologue: stage t0 (dbuf0) and t1 (dbuf1) fully; keep t1 (8) in flight
  STG(gA, 0, 0, sA);                 // t0 A0
  STG(gA, 128, 0, sA + 8192);        // t0 A1
  STG(gB1, 0, 0, sB1);               // t0 B1
  STG(gB2, 0, 0, sB2);               // t0 B2
  STG(gA, 0, 64, sA + 16384);        // t1 A0
  STG(gA, 128, 64, sA + 24576);      // t1 A1
  STG(gB1, 0, 64, sB1 + 8192);       // t1 B1
  STG(gB2, 0, 64, sB2 + 8192);       // t1 B2
  VMCNT8;
  BAR;

  const int NT = D_DIM / 64;  // 32
  for (int t = 0; t < NT; ++t) {
    const int db = t & 1;
    const unsigned short* A0p = sA + (db * 2 + 0) * 8192;
    const unsigned short* A1p = sA + (db * 2 + 1) * 8192;
    const unsigned short* B1p = sB1 + db * 8192;
    const unsigned short* B2p = sB2 + db * 8192;
    const int p1ok = (t + 1 < NT), p2ok = (t + 2 < NT);
    const int tc2 = (t + 2) << 6;
    bf16x8 aA[4][2], aB[4][2], b1[2][2], b2[2][2];

    // ---- P1: read A0+B1 frags; MFMA acc1 mh0 ----
#pragma unroll
    for (int j = 0; j < 4; ++j) {
      aA[j][0] = *(const bf16x8*)(A0p + aoff[j]);
      aA[j][1] = *(const bf16x8*)(A0p + (aoff[j] ^ 32));
    }
#pragma unroll
    for (int g = 0; g < 2; ++g) {
      b1[g][0] = *(const bf16x8*)(B1p + boff[g]);
      b1[g][1] = *(const bf16x8*)(B1p + (boff[g] ^ 32));
    }
    BAR;
    PRIO1;
#pragma unroll
    for (int j = 0; j < 4; ++j)
#pragma unroll
      for (int g = 0; g < 2; ++g) {
        acc1[j][g] = __builtin_amdgcn_mfma_f32_16x16x32_bf16(aA[j][0], b1[g][0], acc1[j][g], 0, 0, 0);
        acc1[j][g] = __builtin_amdgcn_mfma_f32_16x16x32_bf16(aA[j][1], b1[g][1], acc1[j][g], 0, 0, 0);
      }
    PRIO0;
    BAR;

    // ---- P2: read A1 frags; stage (t+2){A0,B1}; MFMA acc1 mh1 ----
#pragma unroll
    for (int j = 0; j < 4; ++j) {
      aB[j][0] = *(const bf16x8*)(A1p + aoff[j]);
      aB[j][1] = *(const bf16x8*)(A1p + (aoff[j] ^ 32));
    }
    if (p2ok) {
      STG(gA, 0, tc2, sA + (db * 2 + 0) * 8192);
      STG(gB1, 0, tc2, sB1 + db * 8192);
    }
    BAR;
    PRIO1;
#pragma unroll
    for (int j = 0; j < 4; ++j)
#pragma unroll
      for (int g = 0; g < 2; ++g) {
        acc1[4 + j][g] = __builtin_amdgcn_mfma_f32_16x16x32_bf16(aB[j][0], b1[g][0], acc1[4 + j][g], 0, 0, 0);
        acc1[4 + j][g] = __builtin_amdgcn_mfma_f32_16x16x32_bf16(aB[j][1], b1[g][1], acc1[4 + j][g], 0, 0, 0);
      }
    PRIO0;
    BAR;

    // ---- P3: read B2 frags; stage (t+2)A1; MFMA acc2 mh0 ----
#pragma unroll
    for (int g = 0; g < 2; ++g) {
      b2[g][0] = *(const bf16x8*)(B2p + boff[g]);
      b2[g][1] = *(const bf16x8*)(B2p + (boff[g] ^ 32));
    }
    if (p2ok) STG(gA, 128, tc2, sA + (db * 2 + 1) * 8192);
    BAR;
    PRIO1;
#pragma unroll
    for (int j = 0; j < 4; ++j)
#pragma unroll
      for (int g = 0; g < 2; ++g) {
        acc2[j][g] = __builtin_amdgcn_mfma_f32_16x16x32_bf16(aA[j][0], b2[g][0], acc2[j][g], 0, 0, 0);
        acc2[j][g] = __builtin_amdgcn_mfma_f32_16x16x32_bf16(aA[j][1], b2[g][1], acc2[j][g], 0, 0, 0);
      }
    PRIO0;
    BAR;

    // ---- P4: stage (t+2)B2; MFMA acc2 mh1 (regs); vmcnt(8) keeps t+2 in flight ----
    if (p2ok) STG(gB2, 0, tc2, sB2 + db * 8192);
    BAR;
    PRIO1;
#pragma unroll
    for (int j = 0; j < 4; ++j)
#pragma unroll
      for (int g = 0; g < 2; ++g) {
        acc2[4 + j][g] = __builtin_amdgcn_mfma_f32_16x16x32_bf16(aB[j][0], b2[g][0], acc2[4 + j][g], 0, 0, 0);
        acc2[4 + j][g] = __builtin_amdgcn_mfma_f32_16x16x32_bf16(aB[j][1], b2[g][1], acc2[4 + j][g], 0, 0, 0);
      }
    PRIO0;
    if (p2ok) { VMCNT8; } else if (p1ok) { VMCNT0; }
    BAR;
  }

  // epilogue: h = silu(x1)*x2, bf16
#pragma unroll
  for (int f = 0; f < 8; ++f)
#pragma unroll
    for (int g = 0; g < 2; ++g)
#pragma unroll
      for (int r = 0; r < 4; ++r) {
        int row = m0 + (f >> 2) * 128 + wm * 64 + (f & 3) * 16 + kq * 4 + r;
        int col = n0 + wn * 32 + g * 16 + lr;
        float x1 = acc1[f][g][r], x2 = acc2[f][g][r];
        float hv = x1 / (1.f + __expf(-x1)) * x2;
        Hb[(long)row * FFN_DIM + col] = f2bf(hv);
      }
#undef STG
}

// ---------- GEMM2: region-confined 4-phase, prefetch t+2, XCD swizzle ----------
// tile 256m x 128n, BK=64, 8 waves 4Mx2N. Reads: p1:{A f01,B g01} p2:{A f23}
// p3:{B g23} p4:{}. Stages (t+2, own dbuf): p3:{A0,A1} p4:{B}; vmcnt(6) at p4.
__global__ __launch_bounds__(512, 2) void gemm2(
    const unsigned short* __restrict__ Hb,    // (4096,8192)
    const unsigned short* __restrict__ W2T,   // (2048,8192)
    float* __restrict__ out) {                // (4096,2048)
  __shared__ __align__(16) unsigned short sA[2 * 2 * 8192];
  __shared__ __align__(16) unsigned short sB[2 * 8192];

  const int tid = threadIdx.x;
  const int wv = tid >> 6, l = tid & 63;
  const int wm = wv >> 1, wn = wv & 1;        // 4M x 2N
  const int kq = l >> 4, lr = l & 15;
  // 256 wg, 32/XCD contiguous, m-fastest
  const int bsw = (blockIdx.x & 7) * 32 + (blockIdx.x >> 3);
  const int m0 = (bsw & 15) << 8;
  const int n0 = (bsw >> 4) << 7;
  const int hA = wm >> 1;

  const int rsub = tid >> 3;
  const int sslot8 = ((tid & 7) ^ ((tid >> 3) & 7)) << 3;
  const unsigned short* gA = Hb  + (long)(m0 + rsub) * FFN_DIM + sslot8;
  const unsigned short* gB = W2T + (long)(n0 + rsub) * FFN_DIM + sslot8;

#define STG2(gbase, rowoff, tc_, lbase) do { \
    gload16((gbase) + (long)(rowoff) * FFN_DIM + (tc_), (lbase) + wv * 512); \
    gload16((gbase) + (long)((rowoff) + 64) * FFN_DIM + (tc_), (lbase) + 4096 + wv * 512); \
  } while (0)

  int aoff[4], boff[4];
#pragma unroll
  for (int f = 0; f < 4; ++f) {
    int row = (wm & 1) * 64 + f * 16 + lr;
    aoff[f] = row * 64 + ((kq ^ (row & 7)) << 3);
  }
#pragma unroll
  for (int g = 0; g < 4; ++g) {
    int row = wn * 64 + g * 16 + lr;
    boff[g] = row * 64 + ((kq ^ (row & 7)) << 3);
  }

  f32x4 acc[4][4];
  f32x4 z = {0.f, 0.f, 0.f, 0.f};
#pragma unroll
  for (int f = 0; f < 4; ++f)
#pragma unroll
    for (int g = 0; g < 4; ++g) acc[f][g] = z;

  // prologue: stage t0 and t1 fully; keep t1 (6) in flight
  STG2(gA, 0, 0, sA);
  STG2(gA, 128, 0, sA + 8192);
  STG2(gB, 0, 0, sB);
  STG2(gA, 0, 64, sA + 16384);
  STG2(gA, 128, 64, sA + 24576);
  STG2(gB, 0, 64, sB + 8192);
  VMCNT6;
  BAR;

  const int NT = FFN_DIM / 64;  // 128
  for (int t = 0; t < NT; ++t) {
    const int db = t & 1;
    const unsigned short* Ap = sA + (db * 2 + hA) * 8192;
    const unsigned short* Bp = sB + db * 8192;
    const int p1ok = (t + 1 < NT), p2ok = (t + 2 < NT);
    const int tc2 = (t + 2) << 6;
    bf16x8 aA[2][2], aB[2][2], bA[2][2], bB[2][2];

    // ---- P1: read A f01 + B g01; MFMA f01xg01 ----
#pragma unroll
    for (int f = 0; f < 2; ++f) {
      aA[f][0] = *(const bf16x8*)(Ap + aoff[f]);
      aA[f][1] = *(const bf16x8*)(Ap + (aoff[f] ^ 32));
    }
#pragma unroll
    for (int g = 0; g < 2; ++g) {
      bA[g][0] = *(const bf16x8*)(Bp + boff[g]);
      bA[g][1] = *(const bf16x8*)(Bp + (boff[g] ^ 32));
    }
    BAR;
    PRIO1;
#pragma unroll
    for (int f = 0; f < 2; ++f)
#pragma unroll
      for (int g = 0; g < 2; ++g) {
        acc[f][g] = __builtin_amdgcn_mfma_f32_16x16x32_bf16(aA[f][0], bA[g][0], acc[f][g], 0, 0, 0);
        acc[f][g] = __builtin_amdgcn_mfma_f32_16x16x32_bf16(aA[f][1], bA[g][1], acc[f][g], 0, 0, 0);
      }
    PRIO0;
    BAR;

    // ---- P2: read A f23; MFMA f23xg01 ----
#pragma unroll
    for (int f = 0; f < 2; ++f) {
      aB[f][0] = *(const bf16x8*)(Ap + aoff[2 + f]);
      aB[f][1] = *(const bf16x8*)(Ap + (aoff[2 + f] ^ 32));
    }
    BAR;
    PRIO1;
#pragma unroll
    for (int f = 0; f < 2; ++f)
#pragma unroll
      for (int g = 0; g < 2; ++g) {
        acc[2 + f][g] = __builtin_amdgcn_mfma_f32_16x16x32_bf16(aB[f][0], bA[g][0], acc[2 + f][g], 0, 0, 0);
        acc[2 + f][g] = __builtin_amdgcn_mfma_f32_16x16x32_bf16(aB[f][1], bA[g][1], acc[2 + f][g], 0, 0, 0);
      }
    PRIO0;
    BAR;

    // ---- P3: read B g23; stage (t+2){A0,A1}; MFMA f01xg23 ----
#pragma unroll
    for (int g = 0; g < 2; ++g) {
      bB[g][0] = *(const bf16x8*)(Bp + boff[2 + g]);
      bB[g][1] = *(const bf16x8*)(Bp + (boff[2 + g] ^ 32));
    }
    if (p2ok) {
      STG2(gA, 0, tc2, sA + (db * 2 + 0) * 8192);
      STG2(gA, 128, tc2, sA + (db * 2 + 1) * 8192);
    }
    BAR;
    PRIO1;
#pragma unroll
    for (int f = 0; f < 2; ++f)
#pragma unroll
      for (int g = 0; g < 2; ++g) {
        acc[f][2 + g] = __builtin_amdgcn_mfma_f32_16x16x32_bf16(aA[f][0], bB[g][0], acc[f][2 + g], 0, 0, 0);
        acc[f][2 + g] = __builtin_amdgcn_mfma_f32_16x16x32_bf16(aA[f][1], bB[g][1], acc[f][2 + g], 0, 0, 0);
      }
    PRIO0;
    BAR;

    // ---- P4: stage (t+2)B; MFMA f23xg23 (regs); vmcnt(6) ----
    if (p2ok) STG2(gB, 0, tc2, sB + db * 8192);
    BAR;
    PRIO1;
#pragma unroll
    for (int f = 0; f < 2; ++f)
#pragma unroll
      for (int g = 0; g < 2; ++g) {
        acc[2 + f][2 + g] = __builtin_amdgcn_mfma_f32_16x16x32_bf16(aB[f][0], bB[g][0], acc[2 + f][2 + g], 0, 0, 0);
        acc[2 + f][2 + g] = __builtin_amdgcn_mfma_f32_16x16x32_bf16(aB[f][1], bB[g][1], acc[2 + f][2 + g], 0, 0, 0);
      }
    PRIO0;
    if (p2ok) { VMCNT6; } else if (p1ok) { VMCNT0; }
    BAR;
  }

#pragma unroll
  for (int f = 0; f < 4; ++f)
#pragma unroll
    for (int g = 0; g < 4; ++g)
#pragma unroll
      for (int r = 0; r < 4; ++r) {
        int row = m0 + wm * 64 + f * 16 + kq * 4 + r;
        int col = n0 + wn * 64 + g * 16 + lr;
        out[(long)row * D_DIM + col] = acc[f][g][r];
      }
#undef STG2
}

extern "C" void kernel_launch(void* const* d_in, const int* in_sizes, int n_in,
                              void* d_out, int out_size, void* d_ws, size_t ws_size,
                              hipStream_t stream) {
  const float* x  = (const float*)d_in[0];
  const float* w1 = (const float*)d_in[1];
  const float* v1 = (const float*)d_in[2];
  const float* w2 = (const float*)d_in[3];
  const int* eidx = (const int*)d_in[4];

  char* ws = (char*)d_ws;
  unsigned short* Xb  = (unsigned short*)(ws);                  // 16 MiB
  unsigned short* W1b = (unsigned short*)(ws + (16l << 20));    // 32 MiB
  unsigned short* V1b = (unsigned short*)(ws + (48l << 20));    // 32 MiB
  unsigned short* W2T = (unsigned short*)(ws + (80l << 20));    // 32 MiB
  unsigned short* Hb  = (unsigned short*)(ws + (112l << 20));   // 64 MiB
  float* out = (float*)d_out;

  long slab = (long)FFN_DIM * D_DIM;
  // order: w2 first, x last, so Xb/W1b/V1b are L3-resident when gemm1 starts
  transpose_kernel<<<dim3(D_DIM / 32, FFN_DIM / 32), 256, 0, stream>>>(w2, eidx, W2T);
  convert_kernel<<<2048, 256, 0, stream>>>(w1, eidx, slab, W1b, slab);
  convert_kernel<<<2048, 256, 0, stream>>>(v1, eidx, slab, V1b, slab);
  convert_kernel<<<2048, 256, 0, stream>>>(x,  eidx, 0,    Xb,  (long)T_DIM * D_DIM);
  gemm1_silu<<<1024, 512, 0, stream>>>(Xb, W1b, V1b, Hb);
  gemm2<<<256, 512, 0, stream>>>(Hb, W2T, out);
}

// Round 11
// 486.465 us; speedup vs baseline: 1.1067x; 1.0085x over previous
//
#include <hip/hip_runtime.h>

#define E_NUM 8
#define FFN_DIM 8192
#define D_DIM 2048
#define T_DIM 4096

using bf16x8 = __attribute__((ext_vector_type(8))) short;
using f32x4  = __attribute__((ext_vector_type(4))) float;
using u16x8  = __attribute__((ext_vector_type(8))) unsigned short;

__device__ __forceinline__ unsigned short f2bf(float f) {
  union { float f; unsigned int u; } v; v.f = f;
  unsigned int u = v.u;
  unsigned int r = (u + 0x7FFFu + ((u >> 16) & 1u)) >> 16;
  return (unsigned short)r;
}

__device__ __forceinline__ void gload16(const unsigned short* g, const unsigned short* l) {
  __builtin_amdgcn_global_load_lds(
      (const __attribute__((address_space(1))) void*)g,
      (__attribute__((address_space(3))) void*)l, 16, 0, 0);
}

// ---------- prep: fp32 -> bf16 convert ----------
__global__ void convert_kernel(const float* __restrict__ src_base,
                               const int* __restrict__ eidx, long slab,
                               unsigned short* __restrict__ dst, long n) {
  const float* src = src_base + (long)(*eidx) * slab;
  long stride = (long)gridDim.x * blockDim.x;
  for (long i = (long)blockIdx.x * blockDim.x + threadIdx.x; i * 8 < n; i += stride) {
    long e = i * 8;
    const float4* p = (const float4*)(src + e);
    float4 f0 = p[0], f1 = p[1];
    u16x8 o;
    o[0] = f2bf(f0.x); o[1] = f2bf(f0.y); o[2] = f2bf(f0.z); o[3] = f2bf(f0.w);
    o[4] = f2bf(f1.x); o[5] = f2bf(f1.y); o[6] = f2bf(f1.z); o[7] = f2bf(f1.w);
    *(u16x8*)(dst + e) = o;
  }
}

// ---------- prep: transpose w2 (FFN,D) fp32 -> (D,FFN) bf16, 64x64 tiles ----------
__global__ __launch_bounds__(512) void transpose_kernel(
    const float* __restrict__ w2, const int* __restrict__ eidx,
    unsigned short* __restrict__ dst) {
  __shared__ unsigned short tile[64][72];
  const float* src = w2 + (long)(*eidx) * (long)FFN_DIM * D_DIM;
  const int tid = threadIdx.x;
  int d0 = blockIdx.x << 6;   // D/64 = 32
  int f0 = blockIdx.y << 6;   // FFN/64 = 128
#pragma unroll
  for (int p = 0; p < 2; ++p) {
    int f = p * 32 + (tid >> 4);
    int dc = (tid & 15) * 4;
    float4 v = *(const float4*)(src + (long)(f0 + f) * D_DIM + d0 + dc);
    tile[f][dc + 0] = f2bf(v.x); tile[f][dc + 1] = f2bf(v.y);
    tile[f][dc + 2] = f2bf(v.z); tile[f][dc + 3] = f2bf(v.w);
  }
  __syncthreads();
  int d = tid >> 3;
  int fc = (tid & 7) * 8;
  u16x8 o;
#pragma unroll
  for (int j = 0; j < 8; ++j) o[j] = tile[fc + j][d];
  *(u16x8*)(dst + (long)(d0 + d) * FFN_DIM + f0 + fc) = o;
}

// Counted vmcnt waits with memory clobber (stage issues pinned to their side
// of the wait so the outstanding-count arithmetic stays exact).
#define VMCNT8 asm volatile("s_waitcnt vmcnt(8)" ::: "memory")
#define VMCNT6 asm volatile("s_waitcnt vmcnt(6)" ::: "memory")
#define VMCNT5 asm volatile("s_waitcnt vmcnt(5)" ::: "memory")
#define VMCNT3 asm volatile("s_waitcnt vmcnt(3)" ::: "memory")
#define VMCNT0 asm volatile("s_waitcnt vmcnt(0)" ::: "memory")
// Barrier = lgkmcnt(0) drain + s_barrier (opaque). Invariant: a ds_read and a
// later global_load_lds stage that overwrites the same LDS rows must be
// separated by one of these barriers — the drain guarantees the read has
// sampled LDS before any wave crosses and issues the overwrite.
#define BAR asm volatile("s_waitcnt lgkmcnt(0)\n\ts_barrier" ::: "memory")
#define PRIO1 __builtin_amdgcn_s_setprio(1)
#define PRIO0 __builtin_amdgcn_s_setprio(0)

// ---------- GEMM1 fused, read-ahead pipelined 4-phase ----------
// tile 256m x 128n(dual), BK=64, 8 waves 2Mx4N, wave 128x32 per GEMM.
// Frag reads >=1 phase ahead of MFMA use: aA(t)@p3(t-1), b1(t)@p4(t-1),
// aB(t)@p1(t), b2(t)@p2(t).
// Stages for t+2 (8 rounds): B1x2@p1, Ax3@p2, Ax1+B2x2@p3.
// One vmcnt(5)@p2 drains exactly tile t+1 (peak 13 outstanding -> 5).
// Same-phase read/stage audit (steady state): P1 reads sA | stages sB1;
// P2 reads sB2 | stages sA (sA reads drained at end-P1 BAR); P3 reads sA[nx]
// | stages sA[db]+sB2[db]; P4 reads sB1[nx] | none. All conflict-free.
// PROLOGUE: pre-reads (b1(0) from sB1[0]) race with P1(0)'s stage of B1(2)
// into sB1[0] unless separated -> extra BAR after pre-reads (r7-r10 bug).
__global__ __launch_bounds__(512, 2) void gemm1_silu(
    const unsigned short* __restrict__ Xb,    // (4096,2048)
    const unsigned short* __restrict__ W1b,   // (8192,2048)
    const unsigned short* __restrict__ V1b,   // (8192,2048)
    unsigned short* __restrict__ Hb) {        // (4096,8192)
  __shared__ __align__(16) unsigned short sA[2 * 16384];   // 256x64 per buf
  __shared__ __align__(16) unsigned short sB1[2 * 8192];   // 128x64
  __shared__ __align__(16) unsigned short sB2[2 * 8192];

  const int tid = threadIdx.x;
  const int wv = tid >> 6, l = tid & 63;
  const int wm = wv >> 2, wn = wv & 3;        // 2M x 4N
  const int kq = l >> 4, lr = l & 15;
  const int bsw = (blockIdx.x & 7) * 128 + (blockIdx.x >> 3);
  const int m0 = (bsw >> 6) << 8;             // 16 m-blocks
  const int n0 = (bsw & 63) << 7;             // 64 n-blocks

  const int rsub = tid >> 3;
  const int sslot8 = ((tid & 7) ^ ((tid >> 3) & 7)) << 3;
  const unsigned short* gA  = Xb  + (long)(m0 + rsub) * D_DIM + sslot8;
  const unsigned short* gB1 = W1b + (long)(n0 + rsub) * D_DIM + sslot8;
  const unsigned short* gB2 = V1b + (long)(n0 + rsub) * D_DIM + sslot8;

#define STG1(gbase, r_, tc_, lbase) \
  gload16((gbase) + (long)((r_) * 64) * D_DIM + (tc_), (lbase) + (r_) * 4096 + wv * 512)

  int aoffA[4], aoffB[4], boff[2];
#pragma unroll
  for (int j = 0; j < 4; ++j) {
    int rowA = wm * 64 + j * 16 + lr;          // A0 half: rows 0-127
    aoffA[j] = rowA * 64 + ((kq ^ (rowA & 7)) << 3);
    int rowB = 128 + wm * 64 + j * 16 + lr;    // A1 half: rows 128-255
    aoffB[j] = rowB * 64 + ((kq ^ (rowB & 7)) << 3);
  }
#pragma unroll
  for (int g = 0; g < 2; ++g) {
    int row = wn * 32 + g * 16 + lr;
    boff[g] = row * 64 + ((kq ^ (row & 7)) << 3);
  }

  f32x4 acc1[8][2], acc2[8][2];
  f32x4 z = {0.f, 0.f, 0.f, 0.f};
#pragma unroll
  for (int f = 0; f < 8; ++f)
#pragma unroll
    for (int g = 0; g < 2; ++g) { acc1[f][g] = z; acc2[f][g] = z; }

  bf16x8 aA[4][2], aB[4][2], b1[2][2], b2[2][2];

  // prologue: stage t0 (8 rounds) + t1 (8); drain t0; pre-read aA(0), b1(0);
  // then BAR so the pre-reads are sampled before P1(0)'s stage can overwrite.
  STG1(gB1, 0, 0, sB1); STG1(gB1, 1, 0, sB1);
  STG1(gA, 0, 0, sA); STG1(gA, 1, 0, sA); STG1(gA, 2, 0, sA); STG1(gA, 3, 0, sA);
  STG1(gB2, 0, 0, sB2); STG1(gB2, 1, 0, sB2);
  STG1(gB1, 0, 64, sB1 + 8192); STG1(gB1, 1, 64, sB1 + 8192);
  STG1(gA, 0, 64, sA + 16384); STG1(gA, 1, 64, sA + 16384);
  STG1(gA, 2, 64, sA + 16384); STG1(gA, 3, 64, sA + 16384);
  STG1(gB2, 0, 64, sB2 + 8192); STG1(gB2, 1, 64, sB2 + 8192);
  VMCNT8;
  BAR;
#pragma unroll
  for (int j = 0; j < 4; ++j) {
    aA[j][0] = *(const bf16x8*)(sA + aoffA[j]);
    aA[j][1] = *(const bf16x8*)(sA + (aoffA[j] ^ 32));
  }
#pragma unroll
  for (int g = 0; g < 2; ++g) {
    b1[g][0] = *(const bf16x8*)(sB1 + boff[g]);
    b1[g][1] = *(const bf16x8*)(sB1 + (boff[g] ^ 32));
  }
  BAR;   // <-- the r7-r10 race fix: pre-reads sampled before first loop stage

  const int NT = D_DIM / 64;  // 32
  for (int t = 0; t < NT; ++t) {
    const int db = t & 1, nx = db ^ 1;
    const unsigned short* Acur  = sA  + db * 16384;
    const unsigned short* Anxt  = sA  + nx * 16384;
    const unsigned short* B1nxt = sB1 + nx * 8192;
    const unsigned short* B2cur = sB2 + db * 8192;
    unsigned short* AcurW  = (unsigned short*)sA  + db * 16384;
    unsigned short* B1curW = (unsigned short*)sB1 + db * 8192;
    unsigned short* B2curW = (unsigned short*)sB2 + db * 8192;
    const int p1ok = (t + 1 < NT), p2ok = (t + 2 < NT);
    const int tc2 = (t + 2) << 6;

    // ---- P1: read aB(t); stage B1(t+2); MFMA acc1 A0xB1 ----
#pragma unroll
    for (int j = 0; j < 4; ++j) {
      aB[j][0] = *(const bf16x8*)(Acur + aoffB[j]);
      aB[j][1] = *(const bf16x8*)(Acur + (aoffB[j] ^ 32));
    }
    if (p2ok) { STG1(gB1, 0, tc2, B1curW); STG1(gB1, 1, tc2, B1curW); }
    PRIO1;
#pragma unroll
    for (int j = 0; j < 4; ++j)
#pragma unroll
      for (int g = 0; g < 2; ++g) {
        acc1[j][g] = __builtin_amdgcn_mfma_f32_16x16x32_bf16(aA[j][0], b1[g][0], acc1[j][g], 0, 0, 0);
        acc1[j][g] = __builtin_amdgcn_mfma_f32_16x16x32_bf16(aA[j][1], b1[g][1], acc1[j][g], 0, 0, 0);
      }
    PRIO0;
    BAR;

    // ---- P2: read b2(t); stage A(t+2) r0-2; MFMA acc1 A1xB1; vmcnt ----
#pragma unroll
    for (int g = 0; g < 2; ++g) {
      b2[g][0] = *(const bf16x8*)(B2cur + boff[g]);
      b2[g][1] = *(const bf16x8*)(B2cur + (boff[g] ^ 32));
    }
    if (p2ok) { STG1(gA, 0, tc2, AcurW); STG1(gA, 1, tc2, AcurW); STG1(gA, 2, tc2, AcurW); }
    PRIO1;
#pragma unroll
    for (int j = 0; j < 4; ++j)
#pragma unroll
      for (int g = 0; g < 2; ++g) {
        acc1[4 + j][g] = __builtin_amdgcn_mfma_f32_16x16x32_bf16(aB[j][0], b1[g][0], acc1[4 + j][g], 0, 0, 0);
        acc1[4 + j][g] = __builtin_amdgcn_mfma_f32_16x16x32_bf16(aB[j][1], b1[g][1], acc1[4 + j][g], 0, 0, 0);
      }
    PRIO0;
    if (p2ok) { VMCNT5; } else if (p1ok) { VMCNT0; }   // tile t+1 fully landed
    BAR;

    // ---- P3: stage A(t+2) r3 + B2(t+2); MFMA acc2 A0xB2; read aA(t+1) ----
    if (p2ok) { STG1(gA, 3, tc2, AcurW); STG1(gB2, 0, tc2, B2curW); STG1(gB2, 1, tc2, B2curW); }
    PRIO1;
#pragma unroll
    for (int j = 0; j < 4; ++j)
#pragma unroll
      for (int g = 0; g < 2; ++g) {
        acc2[j][g] = __builtin_amdgcn_mfma_f32_16x16x32_bf16(aA[j][0], b2[g][0], acc2[j][g], 0, 0, 0);
        acc2[j][g] = __builtin_amdgcn_mfma_f32_16x16x32_bf16(aA[j][1], b2[g][1], acc2[j][g], 0, 0, 0);
      }
    PRIO0;
    if (p1ok) {
#pragma unroll
      for (int j = 0; j < 4; ++j) {
        aA[j][0] = *(const bf16x8*)(Anxt + aoffA[j]);
        aA[j][1] = *(const bf16x8*)(Anxt + (aoffA[j] ^ 32));
      }
    }
    BAR;

    // ---- P4: MFMA acc2 A1xB2; read b1(t+1) ----
    PRIO1;
#pragma unroll
    for (int j = 0; j < 4; ++j)
#pragma unroll
      for (int g = 0; g < 2; ++g) {
        acc2[4 + j][g] = __builtin_amdgcn_mfma_f32_16x16x32_bf16(aB[j][0], b2[g][0], acc2[4 + j][g], 0, 0, 0);
        acc2[4 + j][g] = __builtin_amdgcn_mfma_f32_16x16x32_bf16(aB[j][1], b2[g][1], acc2[4 + j][g], 0, 0, 0);
      }
    PRIO0;
    if (p1ok) {
#pragma unroll
      for (int g = 0; g < 2; ++g) {
        b1[g][0] = *(const bf16x8*)(B1nxt + boff[g]);
        b1[g][1] = *(const bf16x8*)(B1nxt + (boff[g] ^ 32));
      }
    }
    BAR;
  }

  // epilogue: h = silu(x1)*x2, bf16
#pragma unroll
  for (int f = 0; f < 8; ++f)
#pragma unroll
    for (int g = 0; g < 2; ++g)
#pragma unroll
      for (int r = 0; r < 4; ++r) {
        int row = m0 + (f >> 2) * 128 + wm * 64 + (f & 3) * 16 + kq * 4 + r;
        int col = n0 + wn * 32 + g * 16 + lr;
        float x1 = acc1[f][g][r], x2 = acc2[f][g][r];
        float hv = x1 / (1.f + __expf(-x1)) * x2;
        Hb[(long)row * FFN_DIM + col] = f2bf(hv);
      }
#undef STG1
}

// ---------- GEMM2: same read-ahead pipelined 4-phase ----------
// tile 256m x 128n, BK=64, 8 waves 4Mx2N, wave 64x64.
// Reads: aA(t)@p3(t-1), bA(t)@p4(t-1), aB(t)+bB(t)@p1(t).
// Stages t+2 (6 rounds): Bx2+Ax1@p2, Ax3@p3; vmcnt(3)@p2 drains t+1.
// Prologue pre-reads are one barrier away from the first stage (P2(0)) but
// get the defensive BAR anyway (free, once per launch).
__global__ __launch_bounds__(512, 2) void gemm2(
    const unsigned short* __restrict__ Hb,    // (4096,8192)
    const unsigned short* __restrict__ W2T,   // (2048,8192)
    float* __restrict__ out) {                // (4096,2048)
  __shared__ __align__(16) unsigned short sA[2 * 16384];
  __shared__ __align__(16) unsigned short sB[2 * 8192];

  const int tid = threadIdx.x;
  const int wv = tid >> 6, l = tid & 63;
  const int wm = wv >> 1, wn = wv & 1;        // 4M x 2N
  const int kq = l >> 4, lr = l & 15;
  const int bsw = (blockIdx.x & 7) * 32 + (blockIdx.x >> 3);
  const int m0 = (bsw >> 4) << 8;             // 16 m-blocks
  const int n0 = (bsw & 15) << 7;             // 16 n-blocks

  const int rsub = tid >> 3;
  const int sslot8 = ((tid & 7) ^ ((tid >> 3) & 7)) << 3;
  const unsigned short* gA = Hb  + (long)(m0 + rsub) * FFN_DIM + sslot8;
  const unsigned short* gB = W2T + (long)(n0 + rsub) * FFN_DIM + sslot8;

#define STG1(gbase, r_, tc_, lbase) \
  gload16((gbase) + (long)((r_) * 64) * FFN_DIM + (tc_), (lbase) + (r_) * 4096 + wv * 512)

  int aoff[4], boff[4];
#pragma unroll
  for (int f = 0; f < 4; ++f) {
    int row = wm * 64 + f * 16 + lr;
    aoff[f] = row * 64 + ((kq ^ (row & 7)) << 3);
  }
#pragma unroll
  for (int g = 0; g < 4; ++g) {
    int row = wn * 64 + g * 16 + lr;
    boff[g] = row * 64 + ((kq ^ (row & 7)) << 3);
  }

  f32x4 acc[4][4];
  f32x4 z = {0.f, 0.f, 0.f, 0.f};
#pragma unroll
  for (int f = 0; f < 4; ++f)
#pragma unroll
    for (int g = 0; g < 4; ++g) acc[f][g] = z;

  bf16x8 aA[2][2], aB[2][2], bA[2][2], bB[2][2];

  // prologue: stage t0 (6) + t1 (6); drain t0; pre-read aA(0), bA(0); BAR.
  STG1(gB, 0, 0, sB); STG1(gB, 1, 0, sB);
  STG1(gA, 0, 0, sA); STG1(gA, 1, 0, sA); STG1(gA, 2, 0, sA); STG1(gA, 3, 0, sA);
  STG1(gB, 0, 64, sB + 8192); STG1(gB, 1, 64, sB + 8192);
  STG1(gA, 0, 64, sA + 16384); STG1(gA, 1, 64, sA + 16384);
  STG1(gA, 2, 64, sA + 16384); STG1(gA, 3, 64, sA + 16384);
  VMCNT6;
  BAR;
#pragma unroll
  for (int f = 0; f < 2; ++f) {
    aA[f][0] = *(const bf16x8*)(sA + aoff[f]);
    aA[f][1] = *(const bf16x8*)(sA + (aoff[f] ^ 32));
  }
#pragma unroll
  for (int g = 0; g < 2; ++g) {
    bA[g][0] = *(const bf16x8*)(sB + boff[g]);
    bA[g][1] = *(const bf16x8*)(sB + (boff[g] ^ 32));
  }
  BAR;   // defensive: pre-reads sampled before any loop stage

  const int NT = FFN_DIM / 64;  // 128
  for (int t = 0; t < NT; ++t) {
    const int db = t & 1, nx = db ^ 1;
    const unsigned short* Acur = sA + db * 16384;
    const unsigned short* Anxt = sA + nx * 16384;
    const unsigned short* Bcur = sB + db * 8192;
    const unsigned short* Bnxt = sB + nx * 8192;
    unsigned short* AcurW = (unsigned short*)sA + db * 16384;
    unsigned short* BcurW = (unsigned short*)sB + db * 8192;
    const int p1ok = (t + 1 < NT), p2ok = (t + 2 < NT);
    const int tc2 = (t + 2) << 6;

    // ---- P1: read aB(t) + bB(t); MFMA f01xg01 ----
#pragma unroll
    for (int f = 0; f < 2; ++f) {
      aB[f][0] = *(const bf16x8*)(Acur + aoff[2 + f]);
      aB[f][1] = *(const bf16x8*)(Acur + (aoff[2 + f] ^ 32));
    }
#pragma unroll
    for (int g = 0; g < 2; ++g) {
      bB[g][0] = *(const bf16x8*)(Bcur + boff[2 + g]);
      bB[g][1] = *(const bf16x8*)(Bcur + (boff[2 + g] ^ 32));
    }
    PRIO1;
#pragma unroll
    for (int f = 0; f < 2; ++f)
#pragma unroll
      for (int g = 0; g < 2; ++g) {
        acc[f][g] = __builtin_amdgcn_mfma_f32_16x16x32_bf16(aA[f][0], bA[g][0], acc[f][g], 0, 0, 0);
        acc[f][g] = __builtin_amdgcn_mfma_f32_16x16x32_bf16(aA[f][1], bA[g][1], acc[f][g], 0, 0, 0);
      }
    PRIO0;
    BAR;

    // ---- P2: stage B(t+2)x2 + A(t+2) r0; MFMA f23xg01; vmcnt ----
    if (p2ok) { STG1(gB, 0, tc2, BcurW); STG1(gB, 1, tc2, BcurW); STG1(gA, 0, tc2, AcurW); }
    PRIO1;
#pragma unroll
    for (int f = 0; f < 2; ++f)
#pragma unroll
      for (int g = 0; g < 2; ++g) {
        acc[2 + f][g] = __builtin_amdgcn_mfma_f32_16x16x32_bf16(aB[f][0], bA[g][0], acc[2 + f][g], 0, 0, 0);
        acc[2 + f][g] = __builtin_amdgcn_mfma_f32_16x16x32_bf16(aB[f][1], bA[g][1], acc[2 + f][g], 0, 0, 0);
      }
    PRIO0;
    if (p2ok) { VMCNT3; } else if (p1ok) { VMCNT0; }
    BAR;

    // ---- P3: stage A(t+2) r1-3; MFMA f01xg23; read aA(t+1) ----
    if (p2ok) { STG1(gA, 1, tc2, AcurW); STG1(gA, 2, tc2, AcurW); STG1(gA, 3, tc2, AcurW); }
    PRIO1;
#pragma unroll
    for (int f = 0; f < 2; ++f)
#pragma unroll
      for (int g = 0; g < 2; ++g) {
        acc[f][2 + g] = __builtin_amdgcn_mfma_f32_16x16x32_bf16(aA[f][0], bB[g][0], acc[f][2 + g], 0, 0, 0);
        acc[f][2 + g] = __builtin_amdgcn_mfma_f32_16x16x32_bf16(aA[f][1], bB[g][1], acc[f][2 + g], 0, 0, 0);
      }
    PRIO0;
    if (p1ok) {
#pragma unroll
      for (int f = 0; f < 2; ++f) {
        aA[f][0] = *(const bf16x8*)(Anxt + aoff[f]);
        aA[f][1] = *(const bf16x8*)(Anxt + (aoff[f] ^ 32));
      }
    }
    BAR;

    // ---- P4: MFMA f23xg23; read bA(t+1) ----
    PRIO1;
#pragma unroll
    for (int f = 0; f < 2; ++f)
#pragma unroll
      for (int g = 0; g < 2; ++g) {
        acc[2 + f][2 + g] = __builtin_amdgcn_mfma_f32_16x16x32_bf16(aB[f][0], bB[g][0], acc[2 + f][2 + g], 0, 0, 0);
        acc[2 + f][2 + g] = __builtin_amdgcn_mfma_f32_16x16x32_bf16(aB[f][1], bB[g][1], acc[2 + f][2 + g], 0, 0, 0);
      }
    PRIO0;
    if (p1ok) {
#pragma unroll
      for (int g = 0; g < 2; ++g) {
        bA[g][0] = *(const bf16x8*)(Bnxt + boff[g]);
        bA[g][1] = *(const bf16x8*)(Bnxt + (boff[g] ^ 32));
      }
    }
    BAR;
  }

#pragma unroll
  for (int f = 0; f < 4; ++f)
#pragma unroll
    for (int g = 0; g < 4; ++g)
#pragma unroll
      for (int r = 0; r < 4; ++r) {
        int row = m0 + wm * 64 + f * 16 + kq * 4 + r;
        int col = n0 + wn * 64 + g * 16 + lr;
        out[(long)row * D_DIM + col] = acc[f][g][r];
      }
#undef STG1
}

extern "C" void kernel_launch(void* const* d_in, const int* in_sizes, int n_in,
                              void* d_out, int out_size, void* d_ws, size_t ws_size,
                              hipStream_t stream) {
  const float* x  = (const float*)d_in[0];
  const float* w1 = (const float*)d_in[1];
  const float* v1 = (const float*)d_in[2];
  const float* w2 = (const float*)d_in[3];
  const int* eidx = (const int*)d_in[4];

  char* ws = (char*)d_ws;
  unsigned short* Xb  = (unsigned short*)(ws);                  // 16 MiB
  unsigned short* W1b = (unsigned short*)(ws + (16l << 20));    // 32 MiB
  unsigned short* V1b = (unsigned short*)(ws + (48l << 20));    // 32 MiB
  unsigned short* W2T = (unsigned short*)(ws + (80l << 20));    // 32 MiB
  unsigned short* Hb  = (unsigned short*)(ws + (112l << 20));   // 64 MiB
  float* out = (float*)d_out;

  long slab = (long)FFN_DIM * D_DIM;
  transpose_kernel<<<dim3(D_DIM / 64, FFN_DIM / 64), 512, 0, stream>>>(w2, eidx, W2T);
  convert_kernel<<<2048, 256, 0, stream>>>(w1, eidx, slab, W1b, slab);
  convert_kernel<<<2048, 256, 0, stream>>>(v1, eidx, slab, V1b, slab);
  convert_kernel<<<2048, 256, 0, stream>>>(x,  eidx, 0,    Xb,  (long)T_DIM * D_DIM);
  gemm1_silu<<<1024, 512, 0, stream>>>(Xb, W1b, V1b, Hb);
  gemm2<<<256, 512, 0, stream>>>(Hb, W2T, out);
}